// Round 6
// baseline (97.007 us; speedup 1.0000x reference)
//
#include <hip/hip_runtime.h>

// Bidirectional NN-MSE via MFMA — R22: identical resubmit of R20/R21
// diagnostic (both infra failures: Trio nursery, container-failed-twice;
// OOB re-audit clean: max over-issued addr ~1034KB into 256MB ws, no
// barriers, no deadlock path). DIAGNOSTIC — double-pass ref loop.
// R19 post-mortem: hand-held depth-4 counted-vmcnt pipeline (uncompilable-
// away) was NULL vs R13 => exposed-VMEM-latency FALSIFIED. All pipe models
// say the loop should be 3-7us; inferred nn_part ~37us — but nn_part has
// NEVER appeared in a counter row (top-5 all 40us fills). Three nulls from
// an unverified inference => ablate (m164/m177 discipline).
// Probe: run the ref loop TWICE. min is idempotent => ma/mb bit-identical,
// absmax stays 0. Yields (a) Ddur_us = true marginal cost of one loop pass
// (within-probe A/B), (b) nn_part_2x likely becomes top-1 dispatch =>
// first-ever direct counters (VGPR, MfmaUtil, VALUBusy, Occupancy, FETCH).
// Pre-committed: H1 loop-bound: dur 110-118us & nn_part visible ~70us ->
// next round dedupes 4x-redundant A-stream via LDS staging. H2 overhead-
// bound: dur 85-90us, nn_part hidden -> loop already ~5us, time is outside
// loop. H3 split: Ddur +15-20us -> both effects real, attack in size order.
// Each rep: vmcnt(0) drain + voff reset + fresh ISSUE0-3 (no same-dest
// in-flight races between reps).
//
//   loss = w * mean_n min_j ||p_n - g_j||^2 + (1-w) * mean_m min_i ||g_m - p_i||^2
//
// d^2 = qq - 2 q.r + rr inside mfma_f32_32x32x16_bf16 (K=16), 2-term bf16
// split per operand (exact bf16xbf16 products; absmax 0 R2-R19).

#define NPTS   16384
#define QBLK   256                // 4 waves x 2 tiles x 32 queries (QT=2)
#define QCH    (NPTS / QBLK)      // 64 query chunks
#define SSPLIT 8                  // ref splits
#define RBLK   (NPTS / SSPLIT)    // 2048 refs streamed per block (64 tiles)
#define NB1    (2 * QCH * SSPLIT) // 1024 blocks

typedef __attribute__((ext_vector_type(8)))  __bf16 bf16x8;
typedef __attribute__((ext_vector_type(16))) float  floatx16;

union frag16 { __bf16 v[16]; uint4 q[2]; };

// One thread per (role, point): builds A-form (ref) and B-form (query)
// fragments. A-form pre-swizzled in MFMA wave order: uint4 index
// (p>>5)*64 + half*32 + (p&31) -> each wave tile read is one contiguous,
// perfectly-coalesced 1 KB global_load_dwordx4 burst.
__global__ __launch_bounds__(256) void prep_kernel(
    const float* __restrict__ pred, const float* __restrict__ gt,
    uint4* __restrict__ aform, uint4* __restrict__ bform,
    float* __restrict__ out)
{
    const int i = blockIdx.x * 256 + threadIdx.x;   // 0 .. 2*NPTS-1
    if (i == 0) out[0] = 0.0f;
    const int role = (i < NPTS) ? 0 : 1;            // 0=pred, 1=gt
    const int p = i - role * NPTS;
    const float* __restrict__ src = role ? gt : pred;

    const float x = src[p * 3 + 0], y = src[p * 3 + 1], z = src[p * 3 + 2];
    const float nn = x * x + y * y + z * z;
    const __bf16 xh = (__bf16)x, yh = (__bf16)y, zh = (__bf16)z;
    const __bf16 xl = (__bf16)(x - (float)xh);
    const __bf16 yl = (__bf16)(y - (float)yh);
    const __bf16 zl = (__bf16)(z - (float)zh);
    const __bf16 nh = (__bf16)nn;
    const __bf16 nl = (__bf16)(nn - (float)nh);
    const __bf16 one = (__bf16)1.0f;

    frag16 A;
    A.v[0]  = (__bf16)(-2.0f * (float)xh); A.v[1]  = A.v[0];
    A.v[2]  = (__bf16)(-2.0f * (float)xl); A.v[3]  = A.v[2];
    A.v[4]  = (__bf16)(-2.0f * (float)yh); A.v[5]  = A.v[4];
    A.v[6]  = (__bf16)(-2.0f * (float)yl); A.v[7]  = A.v[6];
    A.v[8]  = (__bf16)(-2.0f * (float)zh); A.v[9]  = A.v[8];
    A.v[10] = (__bf16)(-2.0f * (float)zl); A.v[11] = A.v[10];
    A.v[12] = nh;  A.v[13] = nl;  A.v[14] = one;  A.v[15] = one;

    frag16 B;
    B.v[0] = xh;  B.v[1]  = xl;  B.v[2]  = xh;  B.v[3]  = xl;
    B.v[4] = yh;  B.v[5]  = yl;  B.v[6]  = yh;  B.v[7]  = yl;
    B.v[8] = zh;  B.v[9]  = zl;  B.v[10] = zh;  B.v[11] = zl;
    B.v[12] = one; B.v[13] = one; B.v[14] = nh;  B.v[15] = nl;

    uint4* da = aform + (size_t)role * (NPTS * 2)
              + ((p >> 5) * 64 + (p & 31));
    da[0]  = A.q[0];        // half 0 (k=0..7)  at +0
    da[32] = A.q[1];        // half 1 (k=8..15) at +32
    uint4* db = bform + (size_t)role * (NPTS * 2) + p * 2;
    db[0] = B.q[0];
    db[1] = B.q[1];
}

// 2 MFMA into fixed dest banks v[32:63] + 16 v_min3 into "+v"-pinned
// accumulators. A operands are PHYSICAL queue registers (string-pasted).
#define MMB(A0S, A1S, BQ, M)                                                \
    asm volatile(                                                           \
        "v_mfma_f32_32x32x16_bf16 v[32:47], " A0S ", %[B], %[Z]\n\t"        \
        "v_mfma_f32_32x32x16_bf16 v[48:63], " A1S ", %[B], %[Z]\n\t"        \
        "s_nop 7\n\ts_nop 7\n\ts_nop 7\n\ts_nop 7\n\t"                      \
        "v_min3_f32 %[M0],  %[M0],  v32, v48\n\t"                           \
        "v_min3_f32 %[M1],  %[M1],  v33, v49\n\t"                           \
        "v_min3_f32 %[M2],  %[M2],  v34, v50\n\t"                           \
        "v_min3_f32 %[M3],  %[M3],  v35, v51\n\t"                           \
        "v_min3_f32 %[M4],  %[M4],  v36, v52\n\t"                           \
        "v_min3_f32 %[M5],  %[M5],  v37, v53\n\t"                           \
        "v_min3_f32 %[M6],  %[M6],  v38, v54\n\t"                           \
        "v_min3_f32 %[M7],  %[M7],  v39, v55\n\t"                           \
        "v_min3_f32 %[M8],  %[M8],  v40, v56\n\t"                           \
        "v_min3_f32 %[M9],  %[M9],  v41, v57\n\t"                           \
        "v_min3_f32 %[M10], %[M10], v42, v58\n\t"                           \
        "v_min3_f32 %[M11], %[M11], v43, v59\n\t"                           \
        "v_min3_f32 %[M12], %[M12], v44, v60\n\t"                           \
        "v_min3_f32 %[M13], %[M13], v45, v61\n\t"                           \
        "v_min3_f32 %[M14], %[M14], v46, v62\n\t"                           \
        "v_min3_f32 %[M15], %[M15], v47, v63"                               \
        : [M0] "+v"(M[0]),  [M1] "+v"(M[1]),  [M2] "+v"(M[2]),              \
          [M3] "+v"(M[3]),  [M4] "+v"(M[4]),  [M5] "+v"(M[5]),              \
          [M6] "+v"(M[6]),  [M7] "+v"(M[7]),  [M8] "+v"(M[8]),              \
          [M9] "+v"(M[9]),  [M10] "+v"(M[10]), [M11] "+v"(M[11]),           \
          [M12] "+v"(M[12]), [M13] "+v"(M[13]), [M14] "+v"(M[14]),          \
          [M15] "+v"(M[15])                                                 \
        : [B] "v"(BQ), [Z] "v"(zero)                                        \
        : "v32", "v33", "v34", "v35", "v36", "v37", "v38", "v39",           \
          "v40", "v41", "v42", "v43", "v44", "v45", "v46", "v47",           \
          "v48", "v49", "v50", "v51", "v52", "v53", "v54", "v55",           \
          "v56", "v57", "v58", "v59", "v60", "v61", "v62", "v63")

// Issue one A tile-pair (2x 1KB global_load_dwordx4) into queue slot k
// (v[64+8k : 71+8k]) and advance the byte offset by 2048. Volatile + hard
// dests: the compiler can neither move nor model these loads.
#define ISSUE(D0S, D1S, C0, C1, C2, C3, C4, C5, C6, C7)                     \
    asm volatile(                                                           \
        "global_load_dwordx4 " D0S ", %[off], %[base]\n\t"                  \
        "global_load_dwordx4 " D1S ", %[off], %[base] offset:1024\n\t"      \
        "v_add_u32 %[off], 0x800, %[off]"                                   \
        : [off] "+v"(voff)                                                  \
        : [base] "s"(abase)                                                 \
        : C0, C1, C2, C3, C4, C5, C6, C7, "memory")

#define ISSUE0 ISSUE("v[64:67]", "v[68:71]", "v64","v65","v66","v67","v68","v69","v70","v71")
#define ISSUE1 ISSUE("v[72:75]", "v[76:79]", "v72","v73","v74","v75","v76","v77","v78","v79")
#define ISSUE2 ISSUE("v[80:83]", "v[84:87]", "v80","v81","v82","v83","v84","v85","v86","v87")
#define ISSUE3 ISSUE("v[88:91]", "v[92:95]", "v88","v89","v90","v91","v92","v93","v94","v95")

// Counted wait: oldest queue pair complete, 3 pairs (6 loads) stay in flight.
#define WAIT6 asm volatile("s_waitcnt vmcnt(6)" ::: "memory")

__global__ __launch_bounds__(256) void nn_part_kernel(
    const uint4* __restrict__ aform, const uint4* __restrict__ bform,
    float* __restrict__ partial)
{
    const int bx   = blockIdx.x;           // 0..NB1-1
    const int dir  = bx >> 9;              // 0: Q=pred,R=gt ; 1: Q=gt,R=pred
    const int qc   = (bx & 511) >> 3;      // 0..63
    const int s    = bx & 7;               // 0..7
    const int tid  = threadIdx.x;
    const int lane = tid & 63;
    const int wave = tid >> 6;
    const int lid  = lane & 31;
    const int half = lane >> 5;

    // dir 0: queries=pred(role 0), refs=gt(role 1); dir 1 swapped
    const uint4* __restrict__ Aref = aform + (size_t)(dir ? 0 : 1) * (NPTS * 2);
    const uint4* __restrict__ Bqry = bform + (size_t)(dir ? 1 : 0) * (NPTS * 2);

    // ---- two query B-fragments per wave (prebuilt, 16 B/lane) ----
    const int qbase = qc * QBLK + wave * 64;
    const bf16x8 bq0 = __builtin_bit_cast(bf16x8, Bqry[(qbase + lid) * 2 + half]);
    const bf16x8 bq1 = __builtin_bit_cast(bf16x8, Bqry[(qbase + 32 + lid) * 2 + half]);

    floatx16 zero;
#pragma unroll
    for (int k = 0; k < 16; ++k) zero[k] = 0.0f;

    float ma[16], mb[16];
#pragma unroll
    for (int k = 0; k < 16; ++k) { ma[k] = 3.4e38f; mb[k] = 3.4e38f; }

    const uint4* abase = Aref + (size_t)s * (RBLK * 2);

    // ---- DIAGNOSTIC double pass: rep 0 = cold, rep 1 = L2-warm ----
    // min is idempotent: second pass over the same refs leaves ma/mb
    // bit-identical. Ddur_us vs R19 == marginal cost of one loop pass.
    for (int rep = 0; rep < 2; ++rep) {
        // Drain: retires compiler-tracked bq loads (rep 0) / over-issued
        // tail pairs (rep 1) so queue vmcnt counts are exact and no two
        // in-flight loads share a dest VGPR.
        asm volatile("s_waitcnt vmcnt(0)" ::: "memory");

        unsigned voff = (unsigned)((half * 32 + lid) * 16);   // byte offset
        ISSUE0; ISSUE1; ISSUE2; ISSUE3;                       // pairs 0..3

        for (int j = 0; j < 8; ++j) {
            WAIT6; MMB("v[64:67]", "v[68:71]", bq0, ma);
                   MMB("v[64:67]", "v[68:71]", bq1, mb); ISSUE0;
            WAIT6; MMB("v[72:75]", "v[76:79]", bq0, ma);
                   MMB("v[72:75]", "v[76:79]", bq1, mb); ISSUE1;
            WAIT6; MMB("v[80:83]", "v[84:87]", bq0, ma);
                   MMB("v[80:83]", "v[84:87]", bq1, mb); ISSUE2;
            WAIT6; MMB("v[88:91]", "v[92:95]", bq0, ma);
                   MMB("v[88:91]", "v[92:95]", bq1, mb); ISSUE3;
        }
    }
    asm volatile("s_waitcnt vmcnt(0)" ::: "memory");      // retire over-issue

    // ---- tail: in-lane trees + one shuffle each, plain coalesced store ----
    float* pout = partial + ((size_t)((dir * QCH + qc) * SSPLIT + s)) * QBLK
                + wave * 64;
    {
        float a = fminf(fminf(ma[0], ma[1]), fminf(ma[2], ma[3]));
        float b = fminf(fminf(ma[4], ma[5]), fminf(ma[6], ma[7]));
        float c = fminf(fminf(ma[8], ma[9]), fminf(ma[10], ma[11]));
        float d = fminf(fminf(ma[12], ma[13]), fminf(ma[14], ma[15]));
        float v = fminf(fminf(a, b), fminf(c, d));
        v = fminf(v, __shfl_xor(v, 32));
        if (half == 0) pout[lid] = v;
    }
    {
        float a = fminf(fminf(mb[0], mb[1]), fminf(mb[2], mb[3]));
        float b = fminf(fminf(mb[4], mb[5]), fminf(mb[6], mb[7]));
        float c = fminf(fminf(mb[8], mb[9]), fminf(mb[10], mb[11]));
        float d = fminf(fminf(mb[12], mb[13]), fminf(mb[14], mb[15]));
        float v = fminf(fminf(a, b), fminf(c, d));
        v = fminf(v, __shfl_xor(v, 32));
        if (half == 0) pout[32 + lid] = v;
    }
}

// Combine: min over the SSPLIT ref-splits per query, weighted sum into out.
__global__ __launch_bounds__(256) void nn_combine_kernel(
    const float* __restrict__ partial, const float* __restrict__ weight,
    float* __restrict__ out)
{
    const int b   = blockIdx.x;        // 0..127 : dir = b>>6, qc = b&63
    const int dir = b >> 6;
    const int qc  = b & 63;
    const int t   = threadIdx.x;

    const float* p = partial + ((size_t)((dir * QCH + qc) * SSPLIT)) * QBLK;
    float v = p[t];
#pragma unroll
    for (int s = 1; s < SSPLIT; ++s)
        v = fminf(v, p[s * QBLK + t]);

    for (int off = 32; off; off >>= 1) v += __shfl_down(v, off);
    __shared__ float ws[4];
    if ((t & 63) == 0) ws[t >> 6] = v;
    __syncthreads();
    if (t == 0) {
        const float sum = ws[0] + ws[1] + ws[2] + ws[3];
        const float wgt = weight[0];
        const float scale = (dir ? (1.0f - wgt) : wgt) / (3.0f * (float)NPTS);
        atomicAdd(out, sum * scale);
    }
}

extern "C" void kernel_launch(void* const* d_in, const int* in_sizes, int n_in,
                              void* d_out, int out_size, void* d_ws, size_t ws_size,
                              hipStream_t stream) {
    const float* pred   = (const float*)d_in[0];
    const float* gt     = (const float*)d_in[1];
    const float* weight = (const float*)d_in[2];

    // ws: [partial 512 KB][aform 1 MB][bform 1 MB]
    float* partial = (float*)d_ws;                       // 2*QCH*SSPLIT*QBLK f32
    uint4* aform = (uint4*)((char*)d_ws + (size_t)2 * QCH * SSPLIT * QBLK * 4);
    uint4* bform = aform + (size_t)2 * NPTS * 2;

    prep_kernel<<<2 * NPTS / 256, 256, 0, stream>>>(pred, gt, aform, bform,
                                                    (float*)d_out);
    nn_part_kernel<<<NB1, 256, 0, stream>>>(aform, bform, partial);
    nn_combine_kernel<<<2 * QCH, 256, 0, stream>>>(partial, weight, (float*)d_out);
}

// Round 8
// 81.230 us; speedup vs baseline: 1.1942x; 1.1942x over previous
//
#include <hip/hip_runtime.h>

// Bidirectional NN-MSE via MFMA — R24: identical resubmit of R23 (never ran:
// GPUAcquisitionTimeout, broker pool at capacity — no kernel signal).
// Intra-block LDS dedupe of the A-stream.
// R22 diagnostic (double-pass) measured: ONE ref-loop pass = 14.8 us marginal
// (97.0 vs 82.2), and nn_part_2x still < 40 us => nn_part_1x <= 25 us, loop
// ~15 us (NOT the 37 us inferred R16-R21). Remaining ~20 us of dur_us is
// harness reset dispatches + prep/combine/gaps — untouchable from here.
// Loop theory: per CU per pass, 16 waves x 64 KB = 1 MB VMEM for 256 KB
// unique (4 waves/block read the IDENTICAL A-slice); per-wave stream 64 KB
// >> 32 KB L1, so redundancy is L2-served at ~56 B/cyc/CU => ~7.8 us of the
// 15. R19's latency pipeline was null because the path is BANDWIDTH-bound
// by redundancy, not latency-bound. Fix: stage each 16-tile round (16 KB)
// into double-buffered LDS once per block (each wave copies 4 tiles, plain
// C++ loads issued early / ds_writes late, T14 shape), all 4 waves
// ds_read_b128 the canonical linear conflict-free pattern. Per-CU VMEM
// 1 MB -> 256 KB (~1.9 us); LDS 1 MB @ 256 B/cyc ~1.7 us; binding pipe
// becomes VALU min3 (3.4 us). 1 barrier/round, 5/pass; cross-block overlap
// covers barrier stalls. 32 KB LDS/block (4 blocks/CU = 128 <= 160 KB).
// Predict: loop 15 -> 7-9 us => dur 81.5 -> 73-77 us; absmax 0; conflicts ~0.
// If null: redundancy falsified -> next round ablates MMB compute side.
//
//   loss = w * mean_n min_j ||p_n - g_j||^2 + (1-w) * mean_m min_i ||g_m - p_i||^2
//
// d^2 = qq - 2 q.r + rr inside mfma_f32_32x32x16_bf16 (K=16), 2-term bf16
// split per operand (exact bf16xbf16 products; absmax 0 R2-R22).

#define NPTS   16384
#define QBLK   256                // 4 waves x 2 tiles x 32 queries (QT=2)
#define QCH    (NPTS / QBLK)      // 64 query chunks
#define SSPLIT 8                  // ref splits
#define RBLK   (NPTS / SSPLIT)    // 2048 refs streamed per block (64 tiles)
#define NB1    (2 * QCH * SSPLIT) // 1024 blocks

typedef __attribute__((ext_vector_type(8)))  __bf16 bf16x8;
typedef __attribute__((ext_vector_type(16))) float  floatx16;

union frag16 { __bf16 v[16]; uint4 q[2]; };

// One thread per (role, point): builds A-form (ref) and B-form (query)
// fragments. A-form pre-swizzled in MFMA wave order: uint4 index
// (p>>5)*64 + half*32 + (p&31) -> each wave tile read is one contiguous,
// perfectly-coalesced 1 KB burst (now also the LDS staging unit).
__global__ __launch_bounds__(256) void prep_kernel(
    const float* __restrict__ pred, const float* __restrict__ gt,
    uint4* __restrict__ aform, uint4* __restrict__ bform,
    float* __restrict__ out)
{
    const int i = blockIdx.x * 256 + threadIdx.x;   // 0 .. 2*NPTS-1
    if (i == 0) out[0] = 0.0f;
    const int role = (i < NPTS) ? 0 : 1;            // 0=pred, 1=gt
    const int p = i - role * NPTS;
    const float* __restrict__ src = role ? gt : pred;

    const float x = src[p * 3 + 0], y = src[p * 3 + 1], z = src[p * 3 + 2];
    const float nn = x * x + y * y + z * z;
    const __bf16 xh = (__bf16)x, yh = (__bf16)y, zh = (__bf16)z;
    const __bf16 xl = (__bf16)(x - (float)xh);
    const __bf16 yl = (__bf16)(y - (float)yh);
    const __bf16 zl = (__bf16)(z - (float)zh);
    const __bf16 nh = (__bf16)nn;
    const __bf16 nl = (__bf16)(nn - (float)nh);
    const __bf16 one = (__bf16)1.0f;

    frag16 A;
    A.v[0]  = (__bf16)(-2.0f * (float)xh); A.v[1]  = A.v[0];
    A.v[2]  = (__bf16)(-2.0f * (float)xl); A.v[3]  = A.v[2];
    A.v[4]  = (__bf16)(-2.0f * (float)yh); A.v[5]  = A.v[4];
    A.v[6]  = (__bf16)(-2.0f * (float)yl); A.v[7]  = A.v[6];
    A.v[8]  = (__bf16)(-2.0f * (float)zh); A.v[9]  = A.v[8];
    A.v[10] = (__bf16)(-2.0f * (float)zl); A.v[11] = A.v[10];
    A.v[12] = nh;  A.v[13] = nl;  A.v[14] = one;  A.v[15] = one;

    frag16 B;
    B.v[0] = xh;  B.v[1]  = xl;  B.v[2]  = xh;  B.v[3]  = xl;
    B.v[4] = yh;  B.v[5]  = yl;  B.v[6]  = yh;  B.v[7]  = yl;
    B.v[8] = zh;  B.v[9]  = zl;  B.v[10] = zh;  B.v[11] = zl;
    B.v[12] = one; B.v[13] = one; B.v[14] = nh;  B.v[15] = nl;

    uint4* da = aform + (size_t)role * (NPTS * 2)
              + ((p >> 5) * 64 + (p & 31));
    da[0]  = A.q[0];        // half 0 (k=0..7)  at +0
    da[32] = A.q[1];        // half 1 (k=8..15) at +32
    uint4* db = bform + (size_t)role * (NPTS * 2) + p * 2;
    db[0] = B.q[0];
    db[1] = B.q[1];
}

// R13's proven asm block: 2 MFMA into fixed dest banks + 16 v_min3 into
// "+v"-pinned accumulators. a0/a1 are compiler-allocated operands, so the
// compiler inserts the correct lgkmcnt before the block (ds_read data dep).
#define MFMA_MIN_BLOCK(BQ, M)                                               \
    asm volatile(                                                           \
        "v_mfma_f32_32x32x16_bf16 v[32:47], %[A0], %[B], %[Z]\n\t"          \
        "v_mfma_f32_32x32x16_bf16 v[48:63], %[A1], %[B], %[Z]\n\t"          \
        "s_nop 7\n\ts_nop 7\n\ts_nop 7\n\ts_nop 7\n\t"                      \
        "v_min3_f32 %[M0],  %[M0],  v32, v48\n\t"                           \
        "v_min3_f32 %[M1],  %[M1],  v33, v49\n\t"                           \
        "v_min3_f32 %[M2],  %[M2],  v34, v50\n\t"                           \
        "v_min3_f32 %[M3],  %[M3],  v35, v51\n\t"                           \
        "v_min3_f32 %[M4],  %[M4],  v36, v52\n\t"                           \
        "v_min3_f32 %[M5],  %[M5],  v37, v53\n\t"                           \
        "v_min3_f32 %[M6],  %[M6],  v38, v54\n\t"                           \
        "v_min3_f32 %[M7],  %[M7],  v39, v55\n\t"                           \
        "v_min3_f32 %[M8],  %[M8],  v40, v56\n\t"                           \
        "v_min3_f32 %[M9],  %[M9],  v41, v57\n\t"                           \
        "v_min3_f32 %[M10], %[M10], v42, v58\n\t"                           \
        "v_min3_f32 %[M11], %[M11], v43, v59\n\t"                           \
        "v_min3_f32 %[M12], %[M12], v44, v60\n\t"                           \
        "v_min3_f32 %[M13], %[M13], v45, v61\n\t"                           \
        "v_min3_f32 %[M14], %[M14], v46, v62\n\t"                           \
        "v_min3_f32 %[M15], %[M15], v47, v63"                               \
        : [M0] "+v"(M[0]),  [M1] "+v"(M[1]),  [M2] "+v"(M[2]),              \
          [M3] "+v"(M[3]),  [M4] "+v"(M[4]),  [M5] "+v"(M[5]),              \
          [M6] "+v"(M[6]),  [M7] "+v"(M[7]),  [M8] "+v"(M[8]),              \
          [M9] "+v"(M[9]),  [M10] "+v"(M[10]), [M11] "+v"(M[11]),           \
          [M12] "+v"(M[12]), [M13] "+v"(M[13]), [M14] "+v"(M[14]),          \
          [M15] "+v"(M[15])                                                 \
        : [A0] "v"(a0), [A1] "v"(a1), [B] "v"(BQ), [Z] "v"(zero)            \
        : "v32", "v33", "v34", "v35", "v36", "v37", "v38", "v39",           \
          "v40", "v41", "v42", "v43", "v44", "v45", "v46", "v47",           \
          "v48", "v49", "v50", "v51", "v52", "v53", "v54", "v55",           \
          "v56", "v57", "v58", "v59", "v60", "v61", "v62", "v63")

__global__ __launch_bounds__(256) void nn_part_kernel(
    const uint4* __restrict__ aform, const uint4* __restrict__ bform,
    float* __restrict__ partial)
{
    const int bx   = blockIdx.x;           // 0..NB1-1
    const int dir  = bx >> 9;              // 0: Q=pred,R=gt ; 1: Q=gt,R=pred
    const int qc   = (bx & 511) >> 3;      // 0..63
    const int s    = bx & 7;               // 0..7
    const int tid  = threadIdx.x;
    const int lane = tid & 63;
    const int wave = tid >> 6;
    const int lid  = lane & 31;
    const int half = lane >> 5;

    // dir 0: queries=pred(role 0), refs=gt(role 1); dir 1 swapped
    const uint4* __restrict__ Aref = aform + (size_t)(dir ? 0 : 1) * (NPTS * 2);
    const uint4* __restrict__ Bqry = bform + (size_t)(dir ? 1 : 0) * (NPTS * 2);

    // ---- two query B-fragments per wave (prebuilt, 16 B/lane) ----
    const int qbase = qc * QBLK + wave * 64;
    const bf16x8 bq0 = __builtin_bit_cast(bf16x8, Bqry[(qbase + lid) * 2 + half]);
    const bf16x8 bq1 = __builtin_bit_cast(bf16x8, Bqry[(qbase + 32 + lid) * 2 + half]);

    floatx16 zero;
#pragma unroll
    for (int k = 0; k < 16; ++k) zero[k] = 0.0f;

    float ma[16], mb[16];
#pragma unroll
    for (int k = 0; k < 16; ++k) { ma[k] = 3.4e38f; mb[k] = 3.4e38f; }

    // ---- LDS-deduped A-stream: 64 KB slice in 4 rounds of 16 tiles ----
    // Round staged ONCE per block (each wave copies 4 tiles = 4 KB), all
    // 4 waves consume from LDS. Double-buffered; 1 barrier per round.
    __shared__ uint4 sbuf[2][16 * 64];     // 2 x 16 KB
    const uint4* abase = Aref + (size_t)s * (RBLK * 2);

    // prologue: stage round 0 (tiles 0..15; wave w -> tiles 4w..4w+3)
    {
        const uint4* g = abase + (4 * wave) * 64 + lane;
        uint4* d = &sbuf[0][(4 * wave) * 64 + lane];
        d[0]   = g[0];
        d[64]  = g[64];
        d[128] = g[128];
        d[192] = g[192];
    }
    __syncthreads();

    for (int r = 0; r < 4; ++r) {
        const int b = r & 1;

        // stage round r+1: issue loads EARLY (before the MFMA wall) ...
        uint4 st0, st1, st2, st3;
        if (r < 3) {
            const uint4* g = abase + ((r + 1) * 16 + 4 * wave) * 64 + lane;
            st0 = g[0];
            st1 = g[64];
            st2 = g[128];
            st3 = g[192];
        }

        // consume round r: 8 tile-pairs, canonical linear ds_read_b128
        const uint4* sb = &sbuf[b][lane];
#pragma unroll
        for (int j = 0; j < 8; ++j) {
            const bf16x8 a0 = __builtin_bit_cast(bf16x8, sb[(2 * j) * 64]);
            const bf16x8 a1 = __builtin_bit_cast(bf16x8, sb[(2 * j + 1) * 64]);
            MFMA_MIN_BLOCK(bq0, ma);
            MFMA_MIN_BLOCK(bq1, mb);
        }

        // ... and write LATE into the other buffer (T14 shape)
        if (r < 3) {
            uint4* d = &sbuf[b ^ 1][(4 * wave) * 64 + lane];
            d[0]   = st0;
            d[64]  = st1;
            d[128] = st2;
            d[192] = st3;
        }
        // One barrier/round: guarantees (a) round r+1's stage visible to all
        // waves, (b) all waves' reads of buf b done before round r+2 rewrites.
        __syncthreads();
    }

    // ---- tail: in-lane trees + one shuffle each, plain coalesced store ----
    float* pout = partial + ((size_t)((dir * QCH + qc) * SSPLIT + s)) * QBLK
                + wave * 64;
    {
        float a = fminf(fminf(ma[0], ma[1]), fminf(ma[2], ma[3]));
        float b = fminf(fminf(ma[4], ma[5]), fminf(ma[6], ma[7]));
        float c = fminf(fminf(ma[8], ma[9]), fminf(ma[10], ma[11]));
        float d = fminf(fminf(ma[12], ma[13]), fminf(ma[14], ma[15]));
        float v = fminf(fminf(a, b), fminf(c, d));
        v = fminf(v, __shfl_xor(v, 32));
        if (half == 0) pout[lid] = v;
    }
    {
        float a = fminf(fminf(mb[0], mb[1]), fminf(mb[2], mb[3]));
        float b = fminf(fminf(mb[4], mb[5]), fminf(mb[6], mb[7]));
        float c = fminf(fminf(mb[8], mb[9]), fminf(mb[10], mb[11]));
        float d = fminf(fminf(mb[12], mb[13]), fminf(mb[14], mb[15]));
        float v = fminf(fminf(a, b), fminf(c, d));
        v = fminf(v, __shfl_xor(v, 32));
        if (half == 0) pout[32 + lid] = v;
    }
}

// Combine: min over the SSPLIT ref-splits per query, weighted sum into out.
__global__ __launch_bounds__(256) void nn_combine_kernel(
    const float* __restrict__ partial, const float* __restrict__ weight,
    float* __restrict__ out)
{
    const int b   = blockIdx.x;        // 0..127 : dir = b>>6, qc = b&63
    const int dir = b >> 6;
    const int qc  = b & 63;
    const int t   = threadIdx.x;

    const float* p = partial + ((size_t)((dir * QCH + qc) * SSPLIT)) * QBLK;
    float v = p[t];
#pragma unroll
    for (int s = 1; s < SSPLIT; ++s)
        v = fminf(v, p[s * QBLK + t]);

    for (int off = 32; off; off >>= 1) v += __shfl_down(v, off);
    __shared__ float ws[4];
    if ((t & 63) == 0) ws[t >> 6] = v;
    __syncthreads();
    if (t == 0) {
        const float sum = ws[0] + ws[1] + ws[2] + ws[3];
        const float wgt = weight[0];
        const float scale = (dir ? (1.0f - wgt) : wgt) / (3.0f * (float)NPTS);
        atomicAdd(out, sum * scale);
    }
}

extern "C" void kernel_launch(void* const* d_in, const int* in_sizes, int n_in,
                              void* d_out, int out_size, void* d_ws, size_t ws_size,
                              hipStream_t stream) {
    const float* pred   = (const float*)d_in[0];
    const float* gt     = (const float*)d_in[1];
    const float* weight = (const float*)d_in[2];

    // ws: [partial 512 KB][aform 1 MB][bform 1 MB]
    float* partial = (float*)d_ws;                       // 2*QCH*SSPLIT*QBLK f32
    uint4* aform = (uint4*)((char*)d_ws + (size_t)2 * QCH * SSPLIT * QBLK * 4);
    uint4* bform = aform + (size_t)2 * NPTS * 2;

    prep_kernel<<<2 * NPTS / 256, 256, 0, stream>>>(pred, gt, aform, bform,
                                                    (float*)d_out);
    nn_part_kernel<<<NB1, 256, 0, stream>>>(aform, bform, partial);
    nn_combine_kernel<<<2 * QCH, 256, 0, stream>>>(partial, weight, (float*)d_out);
}